// Round 1
// 3696.009 us; speedup vs baseline: 1.3013x; 1.3013x over previous
//
#include <hip/hip_runtime.h>
#include <stdint.h>

// Seq2seq GRU encoder + greedy GRU decoder, single persistent cooperative kernel.
// R3 changes vs R2:
//  - All step-invariant hot data moved into LDS (141 KB/block, 1 block/CU):
//      * encoder phase: this block's 24 enc GRU rows as f32 (96 KB)
//      * decode phase:  this block's 125 lin_w rows as fp8 e4m3fn x256 (125 KB),
//        decoded with v_cvt_pk_f32_fp8 in the logits loop.
//    The global 67 MB bf16 lint copy is GONE -> no more per-step L2 thrash;
//    dec GRU rows (3 MB/XCD) now stay L2-resident.
//  - argmax still exact: f32 recheck of candidate rows (threshold 2e-3 -> 4e-3
//    for the wider fp8 error band, ~17 sigma margin).
//  - enc_emb[X[t+1]] prefetched under the GRU compute; decode phase A reuses
//    the h already staged in LDS by phase B (skips one agent-scope reload).

#define HID 1024
#define SRC_LEN 256
#define MAX_LEN 128
#define VOC 32000
#define EOS_TOK 2u

#define NBLK 256
#define NTHR 256
#define RPB 125            // vocab rows per block = 32000/256

// ---- workspace layout (bytes) ----
#define WS_GCNT   0        // 8 group counters, 128B apart
#define WS_G2     1024     // level-2 counter
#define WS_GEN    1152     // generation
#define WS_GSUM   2048     // u64[128] fixed-point softmax sums
#define WS_GKEY   3072     // u64[128] argmax keys
#define WS_HB     4096     // float[2][1024] double-buffered h
#define WS_EXP    12288    // float[32000] exp(logit)   (same-block only)
#define WS_ZERO   12288    // bytes to memset each call

#define A_SCOPE __HIP_MEMORY_SCOPE_AGENT

#if __has_builtin(__builtin_amdgcn_cvt_pk_f32_fp8) && __has_builtin(__builtin_amdgcn_cvt_pk_fp8_f32)
#define USE_HW_FP8 1
#else
#define USE_HW_FP8 0
#endif

typedef float v2f __attribute__((ext_vector_type(2)));

__device__ inline unsigned ld_a32(const unsigned* p) {
  return __hip_atomic_load((unsigned*)p, __ATOMIC_RELAXED, A_SCOPE);
}
__device__ inline void st_a32(unsigned* p, unsigned v) {
  __hip_atomic_store(p, v, __ATOMIC_RELAXED, A_SCOPE);
}
__device__ inline unsigned long long ld_a64(const unsigned long long* p) {
  return __hip_atomic_load((unsigned long long*)p, __ATOMIC_RELAXED, A_SCOPE);
}
__device__ inline void st_af(float* p, float v) {
  __hip_atomic_store(p, v, __ATOMIC_RELAXED, A_SCOPE);
}

__device__ inline float sigm(float x) { return 1.0f / (1.0f + __expf(-x)); }

// ---- fp8 e4m3fn helpers (values pre-scaled by 256; enc/dec always paired) ----
__device__ inline unsigned fp8_enc1(float v) {
  const unsigned u = __float_as_uint(v);
  const unsigned s = u >> 31;
  unsigned a = u & 0x7FFFFFFFu;
  if (a < 0x3C800000u) return 0u;          // |v| < 2^-6 -> flush to 0
  a += ((a >> 20) & 1u) + 0x7FFFFu;        // RNE to 3 mantissa bits
  const unsigned e = (a >> 23) - 120u;     // inputs bounded (<32): e in 1..15
  return (s << 7) | (e << 3) | ((a >> 20) & 7u);
}
__device__ inline unsigned fp8x4_enc(float4 f) {
#if USE_HW_FP8
  int v = __builtin_amdgcn_cvt_pk_fp8_f32(f.x, f.y, 0, false);
  v = __builtin_amdgcn_cvt_pk_fp8_f32(f.z, f.w, v, true);
  return (unsigned)v;
#else
  return fp8_enc1(f.x) | (fp8_enc1(f.y) << 8) |
         (fp8_enc1(f.z) << 16) | (fp8_enc1(f.w) << 24);
#endif
}
__device__ inline float fp8_dec1(unsigned q) {
  const unsigned m = q & 0x7Fu;
  return m ? __uint_as_float(((m << 20) + 0x3C000000u) | ((q & 0x80u) << 24)) : 0.0f;
}

// two-level sense barrier, RELAXED atomics only (no cache maintenance).
__device__ inline void grid_bar(char* ws) {
  __syncthreads();
  if (threadIdx.x == 0) {
    __atomic_signal_fence(__ATOMIC_SEQ_CST);
    __builtin_amdgcn_s_waitcnt(0);
    unsigned* gen = (unsigned*)(ws + WS_GEN);
    const unsigned g = ld_a32(gen);
    unsigned* gc = (unsigned*)(ws + WS_GCNT + (size_t)(blockIdx.x >> 5) * 128);
    const unsigned old = __hip_atomic_fetch_add(gc, 1u, __ATOMIC_RELAXED, A_SCOPE);
    if (old == 31u) {
      st_a32(gc, 0u);
      __builtin_amdgcn_s_waitcnt(0);
      unsigned* g2 = (unsigned*)(ws + WS_G2);
      const unsigned o2 = __hip_atomic_fetch_add(g2, 1u, __ATOMIC_RELAXED, A_SCOPE);
      if (o2 == 7u) {
        st_a32(g2, 0u);
        __builtin_amdgcn_s_waitcnt(0);
        __hip_atomic_fetch_add(gen, 1u, __ATOMIC_RELAXED, A_SCOPE);
      } else {
        do { __builtin_amdgcn_s_sleep(4); } while (ld_a32(gen) == g);
      }
    } else {
      do { __builtin_amdgcn_s_sleep(4); } while (ld_a32(gen) == g);
    }
    __atomic_signal_fence(__ATOMIC_SEQ_CST);
  }
  __syncthreads();
}

// stage 4KB h vector from ws into LDS via coherent u64 loads
__device__ inline void load_h_lds(float* dst, const float* src, int tid) {
  const unsigned long long* s = (const unsigned long long*)src;
  unsigned long long* d = (unsigned long long*)dst;
  const unsigned long long a = ld_a64(s + 2 * tid);
  const unsigned long long b = ld_a64(s + 2 * tid + 1);
  d[2 * tid] = a;
  d[2 * tid + 1] = b;
}

// one GRU hidden unit: full 1024-dot by one wave over 6 explicit row pointers
__device__ inline float gru6(const float* __restrict__ a0, const float* __restrict__ a1,
                             const float* __restrict__ a2, const float* __restrict__ c0,
                             const float* __restrict__ c1, const float* __restrict__ c2,
                             int lane,
                             const float* __restrict__ sx, const float* __restrict__ sh,
                             float bi0, float bi1, float bi2,
                             float bh0, float bh1, float bh2, float hold) {
  float ai0 = 0.f, ai1 = 0.f, ai2 = 0.f, ah0 = 0.f, ah1 = 0.f, ah2 = 0.f;
#pragma unroll
  for (int i = 0; i < 8; ++i) {
    const int e = 2 * lane + 128 * i;
    const float2 xv = *(const float2*)(sx + e);
    const float2 hv = *(const float2*)(sh + e);
    float2 w;
    w = *(const float2*)(a0 + e); ai0 += w.x * xv.x + w.y * xv.y;
    w = *(const float2*)(a1 + e); ai1 += w.x * xv.x + w.y * xv.y;
    w = *(const float2*)(a2 + e); ai2 += w.x * xv.x + w.y * xv.y;
    w = *(const float2*)(c0 + e); ah0 += w.x * hv.x + w.y * hv.y;
    w = *(const float2*)(c1 + e); ah1 += w.x * hv.x + w.y * hv.y;
    w = *(const float2*)(c2 + e); ah2 += w.x * hv.x + w.y * hv.y;
  }
#pragma unroll
  for (int off = 32; off; off >>= 1) {
    ai0 += __shfl_xor(ai0, off); ai1 += __shfl_xor(ai1, off); ai2 += __shfl_xor(ai2, off);
    ah0 += __shfl_xor(ah0, off); ah1 += __shfl_xor(ah1, off); ah2 += __shfl_xor(ah2, off);
  }
  const float r = sigm(ai0 + bi0 + ah0 + bh0);
  const float z = sigm(ai1 + bi1 + ah1 + bh1);
  const float n = tanhf(ai2 + bi2 + r * (ah2 + bh2));
  return (1.f - z) * n + z * hold;
}

__global__ void __launch_bounds__(NTHR)
seq2seq_kernel(const int* __restrict__ X,
               const float* __restrict__ enc_emb,
               const float* __restrict__ enc_wih, const float* __restrict__ enc_whh,
               const float* __restrict__ enc_bih, const float* __restrict__ enc_bhh,
               const float* __restrict__ dec_emb,
               const float* __restrict__ dec_wih, const float* __restrict__ dec_whh,
               const float* __restrict__ dec_bih, const float* __restrict__ dec_bhh,
               const float* __restrict__ lin_w, const float* __restrict__ lin_b,
               float* __restrict__ out, char* __restrict__ ws) {
  __shared__ float sx[HID];
  __shared__ float sh[HID];
  __shared__ float spart[256];
  __shared__ float slog[128];
  __shared__ float redS[4];
  __shared__ float sbmax;
  __shared__ unsigned long long sball[2];
  // time-shared 128 KB region:
  //   encoder phase: f32 wenc[4][6][1024]   (96 KB)
  //   decode phase : u64 lq[128 k8][128 r]  (128 KB) fp8 e4m3fn x256 lin_w rows
  __shared__ __align__(16) unsigned char dynls[131072];

  const int b = blockIdx.x, tid = threadIdx.x;
  const int q = tid >> 6, lane = tid & 63;
  const int j = 4 * b + q;
  const int vbase = b * RPB;

  unsigned long long* gsum = (unsigned long long*)(ws + WS_GSUM);
  unsigned long long* gkey = (unsigned long long*)(ws + WS_GKEY);
  float* hb = (float*)(ws + WS_HB);
  float* expb = (float*)(ws + WS_EXP);
  float* probs = out + (MAX_LEN + 1);

  // per-wave biases for hidden unit j (gates r,z,n stacked at 0,H,2H)
  float ebi0 = enc_bih[j], ebi1 = enc_bih[HID + j], ebi2 = enc_bih[2 * HID + j];
  float ebh0 = enc_bhh[j], ebh1 = enc_bhh[HID + j], ebh2 = enc_bhh[2 * HID + j];
  float dbi0 = dec_bih[j], dbi1 = dec_bih[HID + j], dbi2 = dec_bih[2 * HID + j];
  float dbh0 = dec_bhh[j], dbh1 = dec_bhh[HID + j], dbh2 = dec_bhh[2 * HID + j];

  if (b == 0 && tid == 0) out[0] = 1.0f;  // SOS

  // ---- P0: stage this block's 24 encoder GRU rows into LDS (f32) ----
  {
    float* wenc = (float*)dynls;
    for (int rr = 0; rr < 24; ++rr) {      // rr = q*6 + g, g in {ih r,z,n, hh r,z,n}
      const int qq = rr / 6, g = rr % 6;
      const int jj = 4 * b + qq;
      const float* src = (g < 3)
          ? (enc_wih + (size_t)(g * HID + jj) * HID)
          : (enc_whh + (size_t)((g - 3) * HID + jj) * HID);
      ((float4*)(wenc + rr * HID))[tid] = ((const float4*)src)[tid];
    }
  }
  grid_bar(ws);

  // ---- encoder: 256 sequential GRU steps, weights read from LDS ----
  {
    const float* wq = (const float*)dynls + q * 6 * HID;
    for (int t = 0; t < SRC_LEN; ++t) {
      const float* hcur = hb + (t & 1) * HID;
      float* hnext = hb + ((t + 1) & 1) * HID;
      ((float4*)sx)[tid] = ((const float4*)(enc_emb + (size_t)X[t] * HID))[tid];
      load_h_lds(sh, hcur, tid);
      // prefetch next token's embedding row; miss hides under the GRU compute
      float4 pf = {0.f, 0.f, 0.f, 0.f};
      if (t + 1 < SRC_LEN)
        pf = ((const float4*)(enc_emb + (size_t)X[t + 1] * HID))[tid];
      __syncthreads();
      const float hold = sh[j];
      const float hnew = gru6(wq, wq + HID, wq + 2 * HID,
                              wq + 3 * HID, wq + 4 * HID, wq + 5 * HID,
                              lane, sx, sh,
                              ebi0, ebi1, ebi2, ebh0, ebh1, ebh2, hold);
      if (lane == 0) st_af(&hnext[j], hnew);
      asm volatile("" :: "v"(pf.x), "v"(pf.y), "v"(pf.z), "v"(pf.w));
      grid_bar(ws);
    }
  }

  // ---- P1: fp8 (e4m3fn, x256) transposed copy of this block's lin_w rows ----
  // layout: lq[k8][r] u64 = 8 fp8 (k = 8*k8..8*k8+7) of row vbase+r.
  // (block-local LDS; the last encoder grid_bar freed the region)
  {
    unsigned* lq32 = (unsigned*)dynls;
    const int k8 = tid >> 1, kh = tid & 1;   // thread covers cols 4*tid..4*tid+3
    for (int rr = 0; rr < RPB; ++rr) {
      float4 f = ((const float4*)(lin_w + (size_t)(vbase + rr) * HID))[tid];
      f.x *= 256.f; f.y *= 256.f; f.z *= 256.f; f.w *= 256.f;
      lq32[(size_t)(k8 * 128 + rr) * 2 + kh] = fp8x4_enc(f);
    }
    unsigned long long* lqz = (unsigned long long*)dynls;
    for (int i = tid; i < 3 * 128; i += NTHR)        // zero pad rows 125..127
      lqz[(i / 3) * 128 + 125 + (i % 3)] = 0ull;
  }
  __syncthreads();

  // ---- greedy decoder ----
  unsigned tok = 1u;   // SOS
  bool done = false;
  const unsigned long long* lq = (const unsigned long long*)dynls;

  for (int t = 0; t <= MAX_LEN; ++t) {
    if (t > 0) {
      const unsigned long long key = ld_a64(&gkey[t - 1]);
      const unsigned nxt = 0xFFFFFFFFu - (unsigned)(key & 0xFFFFFFFFull);
      if (b == 0 && tid == 0) out[t] = done ? (float)EOS_TOK : (float)nxt;
      if (tid < RPB) {
        float p = 0.f;
        if (!done) {
          const unsigned long long sraw = ld_a64(&gsum[t - 1]);
          const double s = (double)sraw * (1.0 / 16777216.0);
          p = expb[vbase + tid] * (float)(1.0 / s);
        }
        probs[(size_t)(t - 1) * VOC + vbase + tid] = p;
      }
      if (!done) tok = nxt;
      done = done || (nxt == EOS_TOK);
    }
    if (t == MAX_LEN) break;
    if (done) {
      for (int s = t; s < MAX_LEN; ++s) {
        if (tid < RPB) probs[(size_t)s * VOC + vbase + tid] = 0.f;
        if (b == 0 && tid == 0) out[s + 1] = (float)EOS_TOK;
      }
      break;
    }

    // ---- phase A: GRU cell on x = relu(dec_emb[tok]) ----
    const float* hcur = hb + (t & 1) * HID;
    float* hnext = hb + ((t + 1) & 1) * HID;
    {
      float4 f = ((const float4*)(dec_emb + (size_t)tok * HID))[tid];
      f.x = fmaxf(f.x, 0.f); f.y = fmaxf(f.y, 0.f);
      f.z = fmaxf(f.z, 0.f); f.w = fmaxf(f.w, 0.f);
      ((float4*)sx)[tid] = f;
    }
    if (t == 0) load_h_lds(sh, hcur, tid);  // t>0: sh still holds h from phase B
    __syncthreads();
    const float hold = sh[j];
    const float hnew = gru6(dec_wih + (size_t)j * HID,
                            dec_wih + (size_t)(HID + j) * HID,
                            dec_wih + (size_t)(2 * HID + j) * HID,
                            dec_whh + (size_t)j * HID,
                            dec_whh + (size_t)(HID + j) * HID,
                            dec_whh + (size_t)(2 * HID + j) * HID,
                            lane, sx, sh,
                            dbi0, dbi1, dbi2, dbh0, dbh1, dbh2, hold);
    if (lane == 0) st_af(&hnext[j], hnew);
    grid_bar(ws);   // S1: h_new visible everywhere

    // ---- phase B: logits for this block's 125 vocab rows (fp8 from LDS) ----
    load_h_lds(sh, hnext, tid);
    if (tid < 128) slog[tid] = -1e30f;
    __syncthreads();

    {
      // two threads per row: r = tid&127 handles k-half kh = tid>>7
      const int r = tid & 127, kh = tid >> 7;
      const unsigned long long* wp = lq + ((size_t)kh << 13) + r;  // kh*64*128
      const float* hp = sh + (kh << 9);
      float acc = 0.f;
#pragma unroll 8
      for (int jj = 0; jj < 64; ++jj) {
        const unsigned long long w = wp[(size_t)jj << 7];
        const float4 h0 = *(const float4*)(hp + (jj << 3));
        const float4 h1 = *(const float4*)(hp + (jj << 3) + 4);
        const unsigned lo = (unsigned)w, hi = (unsigned)(w >> 32);
#if USE_HW_FP8
        const v2f f01 = __builtin_amdgcn_cvt_pk_f32_fp8(lo, false);
        const v2f f23 = __builtin_amdgcn_cvt_pk_f32_fp8(lo, true);
        const v2f f45 = __builtin_amdgcn_cvt_pk_f32_fp8(hi, false);
        const v2f f67 = __builtin_amdgcn_cvt_pk_f32_fp8(hi, true);
        acc += f01.x * h0.x + f01.y * h0.y + f23.x * h0.z + f23.y * h0.w
             + f45.x * h1.x + f45.y * h1.y + f67.x * h1.z + f67.y * h1.w;
#else
        acc += fp8_dec1(lo) * h0.x + fp8_dec1(lo >> 8) * h0.y
             + fp8_dec1(lo >> 16) * h0.z + fp8_dec1(lo >> 24) * h0.w
             + fp8_dec1(hi) * h1.x + fp8_dec1(hi >> 8) * h1.y
             + fp8_dec1(hi >> 16) * h1.z + fp8_dec1(hi >> 24) * h1.w;
#endif
      }
      spart[tid] = acc;
    }
    __syncthreads();
    float e = 0.f;
    if (tid < RPB) {
      const float logit = (spart[tid] + spart[tid + 128]) * (1.f / 256.f)
                        + lin_b[vbase + tid];
      e = __expf(logit);
      expb[vbase + tid] = e;
      slog[tid] = logit;
    }
    float s = e;
#pragma unroll
    for (int off = 32; off; off >>= 1) s += __shfl_xor(s, off);
    if (lane == 0) redS[q] = s;
    __syncthreads();

    // block-local max of approx logits
    if (q == 0) {
      float m = fmaxf(slog[lane], slog[lane + 64]);
#pragma unroll
      for (int off = 32; off; off >>= 1) m = fmaxf(m, __shfl_xor(m, off));
      if (lane == 0) sbmax = m;
    }
    __syncthreads();
    {
      const bool cand = (tid < RPB) && (slog[tid] >= sbmax - 4e-3f);
      const unsigned long long bal = __ballot(cand);
      if (lane == 0 && q < 2) sball[q] = bal;
    }
    __syncthreads();
    // exact-f32 re-check of candidate rows -> global argmax key
    {
      unsigned long long m0 = sball[0], m1 = sball[1];
      unsigned long long bestk = 0ull;
      int c = 0;
      while (m0 | m1) {
        int r;
        if (m0) { r = __ffsll(m0) - 1; m0 &= m0 - 1; }
        else    { r = 64 + __ffsll(m1) - 1; m1 &= m1 - 1; }
        if ((c & 3) == q) {
          const int v = vbase + r;
          const float* wr = lin_w + (size_t)v * HID;
          float acc = 0.f;
#pragma unroll
          for (int i = 0; i < 4; ++i) {
            const float4 f = *(const float4*)(wr + 4 * lane + 256 * i);
            const float4 hv = *(const float4*)(sh + 4 * lane + 256 * i);
            acc += f.x * hv.x + f.y * hv.y + f.z * hv.z + f.w * hv.w;
          }
#pragma unroll
          for (int off = 32; off; off >>= 1) acc += __shfl_xor(acc, off);
          const float logit = acc + lin_b[v];
          const unsigned u = __float_as_uint(logit);
          const unsigned sb = (u & 0x80000000u) ? ~u : (u | 0x80000000u);
          const unsigned long long k =
              ((unsigned long long)sb << 32) | (unsigned long long)(0xFFFFFFFFu - (unsigned)v);
          if (k > bestk) bestk = k;
        }
        ++c;
      }
      if (lane == 0 && bestk) atomicMax(&gkey[t], bestk);
    }
    if (tid == 0) {
      const float st = redS[0] + redS[1] + redS[2] + redS[3];
      atomicAdd(&gsum[t], (unsigned long long)((double)st * 16777216.0));
    }
    grid_bar(ws);   // S2: argmax key + sum globally visible
  }
}

extern "C" void kernel_launch(void* const* d_in, const int* in_sizes, int n_in,
                              void* d_out, int out_size, void* d_ws, size_t ws_size,
                              hipStream_t stream) {
  const int* X = (const int*)d_in[0];
  const float* enc_emb = (const float*)d_in[1];
  const float* enc_wih = (const float*)d_in[2];
  const float* enc_whh = (const float*)d_in[3];
  const float* enc_bih = (const float*)d_in[4];
  const float* enc_bhh = (const float*)d_in[5];
  const float* dec_emb = (const float*)d_in[6];
  const float* dec_wih = (const float*)d_in[7];
  const float* dec_whh = (const float*)d_in[8];
  const float* dec_bih = (const float*)d_in[9];
  const float* dec_bhh = (const float*)d_in[10];
  const float* lin_w = (const float*)d_in[11];
  const float* lin_b = (const float*)d_in[12];
  float* out = (float*)d_out;
  char* ws = (char*)d_ws;

  hipMemsetAsync(d_ws, 0, WS_ZERO, stream);
  void* args[] = { &X, &enc_emb, &enc_wih, &enc_whh, &enc_bih, &enc_bhh,
                   &dec_emb, &dec_wih, &dec_whh, &dec_bih, &dec_bhh,
                   &lin_w, &lin_b, &out, &ws };
  hipLaunchCooperativeKernel((void*)seq2seq_kernel, dim3(NBLK), dim3(NTHR),
                             args, 0, stream);
}